// Round 13
// baseline (1090.172 us; speedup 1.0000x reference)
//
#include <hip/hip_runtime.h>
#include <hip/hip_cooperative_groups.h>
#include <cstdint>
#include <cmath>

namespace cg = cooperative_groups;

#define TD 256
#define TE 256
#define NB 8
#define DD 512
#define DIN 80
#define NMEL 80

typedef unsigned long long u64;

// ===========================================================================
// Shared LDS pool (phases are barrier-separated; attn overlays h1s/av):
//   gemm:    As[64][17] @0 (4352), Bs[16][64] @4352 (4096)          = 8448
//   lstm:    h_s[512]   @0 (2048), part[256]  @2048 (1024)          = 3072
//   attn:    h2s[4][512]@0 (8192), sc[4][256] @8192 (4096),
//            h1s[256*33]@12288 (33792, phase2) / av[8][512]@12288
//            (16384, phase4 — overlaid, never simultaneously live)  = 46080
//   outgemm: As2[64][17]@0 (4352), Bs2[16][80]@4352 (5120)          = 9472
// Pool = 46080 B.
// ===========================================================================
#define SMEM_POOL_BYTES 46080

// ---------------------------------------------------------------------------
// Tiled f32 GEMM + bias body (R10-identical numerics).
// ---------------------------------------------------------------------------
__device__ __forceinline__ void gemm_body(const float* __restrict__ A,
    const float* __restrict__ B, const float* __restrict__ bias,
    float* __restrict__ C, int N, int K, int m0, int n0, char* sm)
{
    float (*As)[17] = (float(*)[17])sm;
    float (*Bs)[64] = (float(*)[64])(sm + 4352);
    const int tid = threadIdx.x;
    const int tx = tid & 15, ty = tid >> 4;
    float acc[4][4] = {};
    for (int k0 = 0; k0 < K; k0 += 16) {
#pragma unroll
        for (int i = 0; i < 4; ++i) {
            int lin = tid + i * 256;
            int k = lin & 15, m = lin >> 4;
            As[m][k] = A[(size_t)(m0 + m) * K + k0 + k];
        }
#pragma unroll
        for (int i = 0; i < 4; ++i) {
            int lin = tid + i * 256;
            int n = lin & 63, k = lin >> 6;
            Bs[k][n] = B[(size_t)(k0 + k) * N + n0 + n];
        }
        __syncthreads();
#pragma unroll
        for (int kk = 0; kk < 16; ++kk) {
            float a0 = As[ty * 4 + 0][kk], a1 = As[ty * 4 + 1][kk];
            float a2 = As[ty * 4 + 2][kk], a3 = As[ty * 4 + 3][kk];
            const float4 b4 = *(const float4*)&Bs[kk][tx * 4];
            acc[0][0] += a0 * b4.x; acc[0][1] += a0 * b4.y; acc[0][2] += a0 * b4.z; acc[0][3] += a0 * b4.w;
            acc[1][0] += a1 * b4.x; acc[1][1] += a1 * b4.y; acc[1][2] += a1 * b4.z; acc[1][3] += a1 * b4.w;
            acc[2][0] += a2 * b4.x; acc[2][1] += a2 * b4.y; acc[2][2] += a2 * b4.z; acc[2][3] += a2 * b4.w;
            acc[3][0] += a3 * b4.x; acc[3][1] += a3 * b4.y; acc[3][2] += a3 * b4.z; acc[3][3] += a3 * b4.w;
        }
        __syncthreads();
    }
    const float4 bv = *(const float4*)&bias[n0 + tx * 4];
#pragma unroll
    for (int i = 0; i < 4; ++i) {
        float4 o;
        o.x = acc[i][0] + bv.x; o.y = acc[i][1] + bv.y;
        o.z = acc[i][2] + bv.z; o.w = acc[i][3] + bv.w;
        *(float4*)&C[(size_t)(m0 + ty * 4 + i) * N + n0 + tx * 4] = o;
    }
}

// ---------------------------------------------------------------------------
// LSTM body (exact R3/R10-measured protocol).
// ---------------------------------------------------------------------------
__device__ __forceinline__ void lstm_body(const float* __restrict__ Zx,
    const float* __restrict__ Wr, float* __restrict__ hs,
    u64* __restrict__ hpub, float* __restrict__ outh, float* __restrict__ outc,
    int wg, char* sm)
{
    float* h_s  = (float*)sm;            // 512 floats
    float* part = (float*)(sm + 2048);   // 256 floats
    const int b = wg & 7;
    const int g = wg >> 3;
    const int tid = threadIdx.x;
    const int wv = tid >> 6;
    const int lane = tid & 63;
    const int gcol = ((lane >> 4) << 9) | (g << 4) | (lane & 15);
    const int col = (g << 4) | (lane & 15);

    float w[128];
    {
        const float* wb = Wr + (size_t)(wv * 128) * 2048 + gcol;
#pragma unroll
        for (int i = 0; i < 128; ++i) w[i] = wb[(size_t)i * 2048];
    }
    float creg = 0.f, hlast = 0.f;
    u64* const pub0 = hpub + (size_t)b * 512;
    u64* const pub1 = hpub + (size_t)(8 + b) * 512;

    for (int t = 0; t < TD; ++t) {
        float zx = 0.f;
        if (wv == 0) zx = Zx[(size_t)(b * TD + t) * 2048 + gcol];

        {
            u64* const pr = (t & 1) ? pub1 : pub0;
            const unsigned stag = (unsigned)t;
            u64 v0 = 0, v1 = 0;
            bool d0 = false, d1 = false;
            for (;;) {
                if (!d0) { v0 = __hip_atomic_load(pr + tid, __ATOMIC_RELAXED, __HIP_MEMORY_SCOPE_AGENT);
                           d0 = ((unsigned)(v0 >> 32) == stag); }
                if (!d1) { v1 = __hip_atomic_load(pr + tid + 256, __ATOMIC_RELAXED, __HIP_MEMORY_SCOPE_AGENT);
                           d1 = ((unsigned)(v1 >> 32) == stag); }
                if (d0 && d1) break;
                __builtin_amdgcn_s_sleep(1);
            }
            h_s[tid]       = __uint_as_float((unsigned)v0);
            h_s[tid + 256] = __uint_as_float((unsigned)v1);
        }
        __syncthreads();

        float acc = 0.f;
        {
            const float4* h4 = (const float4*)(h_s + (wv << 7));
#pragma unroll
            for (int i = 0; i < 32; ++i) {
                float4 h = h4[i];
                acc += w[4 * i + 0] * h.x;
                acc += w[4 * i + 1] * h.y;
                acc += w[4 * i + 2] * h.z;
                acc += w[4 * i + 3] * h.w;
            }
        }
        part[tid] = acc;
        __syncthreads();
        if (wv == 0) {
            float z = part[lane] + part[64 + lane] + part[128 + lane] + part[192 + lane] + zx;
            float zf = __shfl(z, lane + 16);
            float zg = __shfl(z, lane + 32);
            float zo = __shfl(z, lane + 48);
            if (lane < 16) {
                float ig = 1.f / (1.f + expf(-z));
                float fg = 1.f / (1.f + expf(-zf));
                float gg = tanhf(zg);
                float og = 1.f / (1.f + expf(-zo));
                creg = fg * creg + ig * gg;
                hlast = og * tanhf(creg);
                u64 pv = ((u64)(unsigned)(t + 1) << 32) | (u64)__float_as_uint(hlast);
                u64* const pw = (t & 1) ? pub0 : pub1;
                __hip_atomic_store(pw + col, pv, __ATOMIC_RELAXED, __HIP_MEMORY_SCOPE_AGENT);
                hs[(size_t)(b * TD + t) * 512 + col] = hlast;
            }
        }
    }
    if (wv == 0 && lane < 16) {
        outh[b * 512 + col] = hlast;
        outc[b * 512 + col] = creg;
    }
}

// ---------------------------------------------------------------------------
// Fused attention body (R10-identical numerics; h1s/av overlaid in pool).
// ---------------------------------------------------------------------------
__device__ __forceinline__ void attn_body(const float* __restrict__ half1,
    const float* __restrict__ half2, const float* __restrict__ att,
    const float* __restrict__ W3, const float* __restrict__ b3,
    float* __restrict__ wgt, int bb, int d0, char* sm)
{
    float (*h2s)[512] = (float(*)[512])sm;            // @0     (phase 2)
    float (*sc)[256]  = (float(*)[256])(sm + 8192);   // @8192  (phases 2-4)
    float *h1s        = (float*)(sm + 12288);         // @12288 (phase 2 only)
    float (*av)[512]  = (float(*)[512])(sm + 12288);  // @12288 (phase 4 only)
    const int tid = threadIdx.x;
    const float C2 = 2.885390081777927f;  // 2*log2(e)

#pragma unroll
    for (int i = 0; i < 8; ++i) {
        int lin = tid + i * 256;
        int r = lin >> 9, k = lin & 511;
        h2s[r][k] = half2[(size_t)(bb * TD + d0 + r) * 512 + k] * C2;
    }

    float accs[4] = {0.f, 0.f, 0.f, 0.f};
    for (int kc = 0; kc < 512; kc += 32) {
#pragma unroll
        for (int i = 0; i < 32; ++i) {
            int lin = tid + i * 256;
            int e = lin >> 5, kk = lin & 31;
            h1s[e * 33 + kk] = half1[(size_t)(bb * TE + e) * 512 + kc + kk] * C2;
        }
        __syncthreads();   // first pass also covers h2s
        const float* myh1 = h1s + tid * 33;
#pragma unroll 8
        for (int kk = 0; kk < 32; ++kk) {
            float u = myh1[kk];
            float w = W3[kc + kk];
#pragma unroll
            for (int r = 0; r < 4; ++r) {
                float t = 1.f - 2.f * __builtin_amdgcn_rcpf(__builtin_amdgcn_exp2f(u + h2s[r][kc + kk]) + 1.f);
                accs[r] += t * w;
            }
        }
        __syncthreads();
    }
    {
        const float b3v = b3[0];
#pragma unroll
        for (int r = 0; r < 4; ++r) sc[r][tid] = accs[r] + b3v;
    }
    __syncthreads();
    {
        const int r = tid >> 6, l = tid & 63;
        float4 v = *(const float4*)&sc[r][l * 4];
        float mx = fmaxf(fmaxf(v.x, v.y), fmaxf(v.z, v.w));
#pragma unroll
        for (int off = 32; off; off >>= 1) mx = fmaxf(mx, __shfl_xor(mx, off));
        const float L2E = 1.44269504089f;
        float e0 = __builtin_amdgcn_exp2f((v.x - mx) * L2E);
        float e1 = __builtin_amdgcn_exp2f((v.y - mx) * L2E);
        float e2 = __builtin_amdgcn_exp2f((v.z - mx) * L2E);
        float e3 = __builtin_amdgcn_exp2f((v.w - mx) * L2E);
        float s = e0 + e1 + e2 + e3;
#pragma unroll
        for (int off = 32; off; off >>= 1) s += __shfl_xor(s, off);
        float inv = 1.f / s;
        float4 p; p.x = e0 * inv; p.y = e1 * inv; p.z = e2 * inv; p.w = e3 * inv;
        *(float4*)&sc[r][l * 4] = p;
    }
    __syncthreads();   // h1s dead from here; av may now reuse @12288
    float acc[4][2] = {};
    for (int e0 = 0; e0 < TE; e0 += 8) {
#pragma unroll
        for (int i = 0; i < 16; ++i) {
            int lin = tid + i * 256;
            int e = lin >> 9, k = lin & 511;
            av[e][k] = att[(size_t)(bb * TE + e0 + e) * 512 + k];
        }
        __syncthreads();
#pragma unroll
        for (int ee = 0; ee < 8; ++ee) {
            float x0 = av[ee][tid], x1 = av[ee][tid + 256];
#pragma unroll
            for (int r = 0; r < 4; ++r) {
                float p = sc[r][e0 + ee];
                acc[r][0] += p * x0;
                acc[r][1] += p * x1;
            }
        }
        __syncthreads();
    }
#pragma unroll
    for (int r = 0; r < 4; ++r) {
        wgt[(size_t)(bb * TD + d0 + r) * 512 + tid] = acc[r][0];
        wgt[(size_t)(bb * TD + d0 + r) * 512 + tid + 256] = acc[r][1];
    }
}

// ---------------------------------------------------------------------------
// outgemm body (R10-identical).
// ---------------------------------------------------------------------------
__device__ __forceinline__ void outgemm_body(const float* __restrict__ x,
    const float* __restrict__ wgt, const float* __restrict__ Wout,
    const float* __restrict__ bout, float* __restrict__ out, int m0, int ks,
    char* sm)
{
    float (*As2)[17] = (float(*)[17])sm;
    float (*Bs2)[80] = (float(*)[80])(sm + 4352);
    const int tid = threadIdx.x;
    const int tx = tid & 15, ty = tid >> 4;
    float acc[4][5] = {};
    for (int kt = 0; kt < 16; ++kt) {
        const int k0 = ks * 256 + kt * 16;
        const float* src = (k0 < 512) ? x : wgt;
        const int kk0 = (k0 < 512) ? k0 : (k0 - 512);
#pragma unroll
        for (int i = 0; i < 4; ++i) {
            int lin = tid + i * 256;
            int k = lin & 15, m = lin >> 4;
            As2[m][k] = src[(size_t)(m0 + m) * 512 + kk0 + k];
        }
#pragma unroll
        for (int i = 0; i < 5; ++i) {
            int lin = tid + i * 256;
            int n = lin % 80, k = lin / 80;
            Bs2[k][n] = Wout[(size_t)(k0 + k) * 80 + n];
        }
        __syncthreads();
#pragma unroll
        for (int kk = 0; kk < 16; ++kk) {
            float a[4], bv[5];
#pragma unroll
            for (int i = 0; i < 4; ++i) a[i] = As2[ty * 4 + i][kk];
#pragma unroll
            for (int j = 0; j < 5; ++j) bv[j] = Bs2[kk][tx * 5 + j];
#pragma unroll
            for (int i = 0; i < 4; ++i)
#pragma unroll
                for (int j = 0; j < 5; ++j) acc[i][j] += a[i] * bv[j];
        }
        __syncthreads();
    }
#pragma unroll
    for (int i = 0; i < 4; ++i) {
#pragma unroll
        for (int j = 0; j < 5; ++j) {
            float v = acc[i][j];
            if (ks == 0) v += bout[tx * 5 + j];
            atomicAdd(&out[(size_t)(m0 + ty * 4 + i) * 80 + tx * 5 + j], v);
        }
    }
}

// ---------------------------------------------------------------------------
// MEGA kernel: whole pipeline, one cooperative launch, cg grid barriers.
// ---------------------------------------------------------------------------
__global__ __launch_bounds__(256, 1) void mega_k(
    const float* __restrict__ inputs, const float* __restrict__ Wk,
    const float* __restrict__ lb, const float* __restrict__ att,
    const float* __restrict__ W1, const float* __restrict__ b1,
    const float* __restrict__ Wr, const float* __restrict__ W3,
    const float* __restrict__ b3, const float* __restrict__ Wout,
    const float* __restrict__ bout,
    float* __restrict__ Zx, float* __restrict__ half1,
    float* __restrict__ half2, float* __restrict__ hsx,
    float* __restrict__ wgt, u64* __restrict__ hpub,
    float* __restrict__ out, float* __restrict__ outh, float* __restrict__ outc)
{
    __shared__ __align__(16) char smem[SMEM_POOL_BYTES];
    const int wg = blockIdx.x;
    cg::grid_group grid = cg::this_grid();

    // P0: pre-GEMMs (5 tile-jobs per WG)
    for (int job = wg; job < 1280; job += 256) {
        if (job < 1024)
            gemm_body(inputs, Wk, lb, Zx, 2048, 80, (job >> 5) * 64, (job & 31) * 64, smem);
        else {
            int j = job - 1024;
            gemm_body(att, W1, b1, half1, 512, 512, (j >> 3) * 64, (j & 7) * 64, smem);
        }
    }
    grid.sync();

    // P1: LSTM
    lstm_body(Zx, Wr, hsx, hpub, outh, outc, wg, smem);
    grid.sync();

    // P2: half2 = hsx @ W1 + b1
    gemm_body(hsx, W1, b1, half2, 512, 512, (wg >> 3) * 64, (wg & 7) * 64, smem);
    grid.sync();

    // P3: attention (2 jobs per WG)
    for (int job = wg; job < 512; job += 256)
        attn_body(half1, half2, att, W3, b3, wgt, job >> 6, (job & 63) * 4, smem);
    grid.sync();

    // P4: outgemm (WGs 0-127)
    if (wg < 128)
        outgemm_body(hsx, wgt, Wout, bout, out, (wg >> 2) * 64, wg & 3, smem);
}

// ---------------------------------------------------------------------------
// Fallback standalone kernels (R10-passing structure).
// ---------------------------------------------------------------------------
__global__ __launch_bounds__(256) void gemm_bias_k(const float* __restrict__ A,
    const float* __restrict__ B, const float* __restrict__ bias,
    float* __restrict__ C, int N, int K)
{
    __shared__ __align__(16) char pool[8448];
    gemm_body(A, B, bias, C, N, K, blockIdx.y * 64, blockIdx.x * 64, pool);
}

__global__ __launch_bounds__(256) void fused_pre_k(
    const float* __restrict__ inputs, const float* __restrict__ Wk,
    const float* __restrict__ lb, float* __restrict__ Zx,
    const float* __restrict__ att, const float* __restrict__ W1,
    const float* __restrict__ b1, float* __restrict__ half1)
{
    __shared__ __align__(16) char pool[8448];
    int wg = blockIdx.x;
    if (wg < 1024)
        gemm_body(inputs, Wk, lb, Zx, 2048, 80, (wg >> 5) * 64, (wg & 31) * 64, pool);
    else {
        wg -= 1024;
        gemm_body(att, W1, b1, half1, 512, 512, (wg >> 3) * 64, (wg & 7) * 64, pool);
    }
}

__global__ __launch_bounds__(256, 1) void lstm_k(const float* __restrict__ Zx,
    const float* __restrict__ Wr, float* __restrict__ hs,
    u64* __restrict__ hpub, float* __restrict__ outh, float* __restrict__ outc)
{
    __shared__ __align__(16) char pool[3072];
    lstm_body(Zx, Wr, hs, hpub, outh, outc, blockIdx.x, pool);
}

__global__ __launch_bounds__(256) void attn_k(const float* __restrict__ half1,
    const float* __restrict__ half2, const float* __restrict__ att,
    const float* __restrict__ W3, const float* __restrict__ b3,
    float* __restrict__ wgt)
{
    __shared__ __align__(16) char pool[SMEM_POOL_BYTES];
    attn_body(half1, half2, att, W3, b3, wgt, blockIdx.x >> 6,
              (blockIdx.x & 63) * 4, pool);
}

__global__ __launch_bounds__(256) void outgemm_k(const float* __restrict__ x,
    const float* __restrict__ wgt, const float* __restrict__ Wout,
    const float* __restrict__ bout, float* __restrict__ out)
{
    __shared__ __align__(16) char pool[9472];
    outgemm_body(x, wgt, Wout, bout, out, blockIdx.x * 64, blockIdx.y, pool);
}

// ---------------------------------------------------------------------------
extern "C" void kernel_launch(void* const* d_in, const int* in_sizes, int n_in,
                              void* d_out, int out_size, void* d_ws, size_t ws_size,
                              hipStream_t stream)
{
    (void)in_sizes; (void)n_in; (void)out_size; (void)ws_size;
    const float* inputs = (const float*)d_in[0];   // [8,256,80]
    const float* att    = (const float*)d_in[1];   // [8,256,512]
    const float* Wk     = (const float*)d_in[2];   // [80,2048]
    const float* Wr     = (const float*)d_in[3];   // [512,2048]
    const float* lb     = (const float*)d_in[4];   // [2048]
    const float* W1     = (const float*)d_in[5];   // [512,512]
    const float* b1     = (const float*)d_in[6];   // [512]
    const float* W3     = (const float*)d_in[7];   // [512]
    const float* b3     = (const float*)d_in[8];   // [1]
    const float* Wout   = (const float*)d_in[9];   // [1024,80]
    const float* bout   = (const float*)d_in[10];  // [80]

    float* out  = (float*)d_out;          // [2048,80]
    float* outh = out + 2048 * 80;        // [8,512]
    float* outc = outh + 8 * 512;         // [8,512]

    char* ws = (char*)d_ws;
    float* Zx    = (float*)(ws);                      // 16 MB  [2048,2048]
    float* half1 = (float*)(ws + (16u << 20));        // 4 MB   [2048,512]
    float* half2 = (float*)(ws + (20u << 20));        // 4 MB   [2048,512]
    float* hsx   = (float*)(ws + (24u << 20));        // 4 MB   [2048,512]
    float* wgt   = (float*)(ws + (28u << 20));        // 4 MB   [2048,512]
    u64*   hpub  = (u64*)(ws + (32u << 20));          // 64 KB  hpub[2][8][512]

    // zero hpub tags; zero out (atomicAdd target)
    (void)hipMemsetAsync(ws + (32u << 20), 0, 65536, stream);
    (void)hipMemsetAsync(d_out, 0, (size_t)2048 * 80 * 4, stream);

    void* args[] = {
        (void*)&inputs, (void*)&Wk, (void*)&lb, (void*)&att, (void*)&W1,
        (void*)&b1, (void*)&Wr, (void*)&W3, (void*)&b3, (void*)&Wout,
        (void*)&bout, (void*)&Zx, (void*)&half1, (void*)&half2, (void*)&hsx,
        (void*)&wgt, (void*)&hpub, (void*)&out, (void*)&outh, (void*)&outc
    };
    hipError_t cerr = hipLaunchCooperativeKernel((void*)mega_k, dim3(256),
                                                 dim3(256), args, 0, stream);
    if (cerr != hipSuccess) {
        // Deterministic fallback: the R10-passing 5-kernel chain.
        fused_pre_k<<<dim3(1280), 256, 0, stream>>>(inputs, Wk, lb, Zx, att, W1, b1, half1);
        void* largs[] = { (void*)&Zx, (void*)&Wr, (void*)&hsx, (void*)&hpub,
                          (void*)&outh, (void*)&outc };
        (void)hipLaunchCooperativeKernel((void*)lstm_k, dim3(256), dim3(256), largs, 0, stream);
        gemm_bias_k<<<dim3(8, 32), 256, 0, stream>>>(hsx, W1, b1, half2, 512, 512);
        attn_k<<<dim3(512), 256, 0, stream>>>(half1, half2, att, W3, b3, wgt);
        outgemm_k<<<dim3(32, 4), 256, 0, stream>>>(hsx, wgt, Wout, bout, out);
    }
}

// Round 14
// 814.334 us; speedup vs baseline: 1.3387x; 1.3387x over previous
//
#include <hip/hip_runtime.h>
#include <cstdint>
#include <cmath>

#define TD 256
#define TE 256
#define NB 8
#define DD 512
#define DIN 80
#define NMEL 80

typedef unsigned long long u64;

// ---------------------------------------------------------------------------
// Tiled f32 GEMM + bias body (R10-identical numerics). Pool: 8448 B.
// ---------------------------------------------------------------------------
__device__ __forceinline__ void gemm_body(const float* __restrict__ A,
    const float* __restrict__ B, const float* __restrict__ bias,
    float* __restrict__ C, int N, int K, int m0, int n0, char* sm)
{
    float (*As)[17] = (float(*)[17])sm;
    float (*Bs)[64] = (float(*)[64])(sm + 4352);
    const int tid = threadIdx.x;
    const int tx = tid & 15, ty = tid >> 4;
    float acc[4][4] = {};
    for (int k0 = 0; k0 < K; k0 += 16) {
#pragma unroll
        for (int i = 0; i < 4; ++i) {
            int lin = tid + i * 256;
            int k = lin & 15, m = lin >> 4;
            As[m][k] = A[(size_t)(m0 + m) * K + k0 + k];
        }
#pragma unroll
        for (int i = 0; i < 4; ++i) {
            int lin = tid + i * 256;
            int n = lin & 63, k = lin >> 6;
            Bs[k][n] = B[(size_t)(k0 + k) * N + n0 + n];
        }
        __syncthreads();
#pragma unroll
        for (int kk = 0; kk < 16; ++kk) {
            float a0 = As[ty * 4 + 0][kk], a1 = As[ty * 4 + 1][kk];
            float a2 = As[ty * 4 + 2][kk], a3 = As[ty * 4 + 3][kk];
            const float4 b4 = *(const float4*)&Bs[kk][tx * 4];
            acc[0][0] += a0 * b4.x; acc[0][1] += a0 * b4.y; acc[0][2] += a0 * b4.z; acc[0][3] += a0 * b4.w;
            acc[1][0] += a1 * b4.x; acc[1][1] += a1 * b4.y; acc[1][2] += a1 * b4.z; acc[1][3] += a1 * b4.w;
            acc[2][0] += a2 * b4.x; acc[2][1] += a2 * b4.y; acc[2][2] += a2 * b4.z; acc[2][3] += a2 * b4.w;
            acc[3][0] += a3 * b4.x; acc[3][1] += a3 * b4.y; acc[3][2] += a3 * b4.z; acc[3][3] += a3 * b4.w;
        }
        __syncthreads();
    }
    const float4 bv = *(const float4*)&bias[n0 + tx * 4];
#pragma unroll
    for (int i = 0; i < 4; ++i) {
        float4 o;
        o.x = acc[i][0] + bv.x; o.y = acc[i][1] + bv.y;
        o.z = acc[i][2] + bv.z; o.w = acc[i][3] + bv.w;
        *(float4*)&C[(size_t)(m0 + ty * 4 + i) * N + n0 + tx * 4] = o;
    }
}

// ---------------------------------------------------------------------------
// LSTM body — R3/R10-measured structure; ONLY change: 16-lane gate math uses
// HW v_exp_f32/v_rcp_f32 (exp2-based sigmoid/tanh) instead of libm calls,
// shortening the serial chain ahead of the publish store. Pool: 3072 B.
// ---------------------------------------------------------------------------
__device__ __forceinline__ void lstm_body(const float* __restrict__ Zx,
    const float* __restrict__ Wr, float* __restrict__ hs,
    u64* __restrict__ hpub, float* __restrict__ outh, float* __restrict__ outc,
    int wg, char* sm)
{
    float* h_s  = (float*)sm;            // 512 floats
    float* part = (float*)(sm + 2048);   // 256 floats
    const int b = wg & 7;
    const int g = wg >> 3;
    const int tid = threadIdx.x;
    const int wv = tid >> 6;
    const int lane = tid & 63;
    const int gcol = ((lane >> 4) << 9) | (g << 4) | (lane & 15);
    const int col = (g << 4) | (lane & 15);
    const float L2E = 1.442695040888963f;

    float w[128];
    {
        const float* wb = Wr + (size_t)(wv * 128) * 2048 + gcol;
#pragma unroll
        for (int i = 0; i < 128; ++i) w[i] = wb[(size_t)i * 2048];
    }
    float creg = 0.f, hlast = 0.f;
    u64* const pub0 = hpub + (size_t)b * 512;
    u64* const pub1 = hpub + (size_t)(8 + b) * 512;

    for (int t = 0; t < TD; ++t) {
        float zx = 0.f;
        if (wv == 0) zx = Zx[(size_t)(b * TD + t) * 2048 + gcol];

        {
            u64* const pr = (t & 1) ? pub1 : pub0;
            const unsigned stag = (unsigned)t;
            u64 v0 = 0, v1 = 0;
            bool d0 = false, d1 = false;
            for (;;) {
                if (!d0) { v0 = __hip_atomic_load(pr + tid, __ATOMIC_RELAXED, __HIP_MEMORY_SCOPE_AGENT);
                           d0 = ((unsigned)(v0 >> 32) == stag); }
                if (!d1) { v1 = __hip_atomic_load(pr + tid + 256, __ATOMIC_RELAXED, __HIP_MEMORY_SCOPE_AGENT);
                           d1 = ((unsigned)(v1 >> 32) == stag); }
                if (d0 && d1) break;
                __builtin_amdgcn_s_sleep(1);
            }
            h_s[tid]       = __uint_as_float((unsigned)v0);
            h_s[tid + 256] = __uint_as_float((unsigned)v1);
        }
        __syncthreads();

        float acc = 0.f;
        {
            const float4* h4 = (const float4*)(h_s + (wv << 7));
#pragma unroll
            for (int i = 0; i < 32; ++i) {
                float4 h = h4[i];
                acc += w[4 * i + 0] * h.x;
                acc += w[4 * i + 1] * h.y;
                acc += w[4 * i + 2] * h.z;
                acc += w[4 * i + 3] * h.w;
            }
        }
        part[tid] = acc;
        __syncthreads();
        if (wv == 0) {
            float z = part[lane] + part[64 + lane] + part[128 + lane] + part[192 + lane] + zx;
            float zf = __shfl(z, lane + 16);
            float zg = __shfl(z, lane + 32);
            float zo = __shfl(z, lane + 48);
            if (lane < 16) {
                float ig = __builtin_amdgcn_rcpf(1.f + __builtin_amdgcn_exp2f(-z  * L2E));
                float fg = __builtin_amdgcn_rcpf(1.f + __builtin_amdgcn_exp2f(-zf * L2E));
                float gg = fmaf(2.f, __builtin_amdgcn_rcpf(1.f + __builtin_amdgcn_exp2f(-2.f * L2E * zg)), -1.f);
                float og = __builtin_amdgcn_rcpf(1.f + __builtin_amdgcn_exp2f(-zo * L2E));
                creg = fmaf(fg, creg, ig * gg);
                float th = fmaf(2.f, __builtin_amdgcn_rcpf(1.f + __builtin_amdgcn_exp2f(-2.f * L2E * creg)), -1.f);
                hlast = og * th;
                u64 pv = ((u64)(unsigned)(t + 1) << 32) | (u64)__float_as_uint(hlast);
                u64* const pw = (t & 1) ? pub0 : pub1;
                __hip_atomic_store(pw + col, pv, __ATOMIC_RELAXED, __HIP_MEMORY_SCOPE_AGENT);
                hs[(size_t)(b * TD + t) * 512 + col] = hlast;
            }
        }
    }
    if (wv == 0 && lane < 16) {
        outh[b * 512 + col] = hlast;
        outc[b * 512 + col] = creg;
    }
}

// ---------------------------------------------------------------------------
// Fused attention body (R10-identical numerics; h1s/av overlaid). Pool 46080 B.
// ---------------------------------------------------------------------------
__device__ __forceinline__ void attn_body(const float* __restrict__ half1,
    const float* __restrict__ half2, const float* __restrict__ att,
    const float* __restrict__ W3, const float* __restrict__ b3,
    float* __restrict__ wgt, int bb, int d0, char* sm)
{
    float (*h2s)[512] = (float(*)[512])sm;            // @0
    float (*sc)[256]  = (float(*)[256])(sm + 8192);   // @8192
    float *h1s        = (float*)(sm + 12288);         // @12288 (phase 2 only)
    float (*av)[512]  = (float(*)[512])(sm + 12288);  // @12288 (phase 4 only)
    const int tid = threadIdx.x;
    const float C2 = 2.885390081777927f;  // 2*log2(e)

#pragma unroll
    for (int i = 0; i < 8; ++i) {
        int lin = tid + i * 256;
        int r = lin >> 9, k = lin & 511;
        h2s[r][k] = half2[(size_t)(bb * TD + d0 + r) * 512 + k] * C2;
    }

    float accs[4] = {0.f, 0.f, 0.f, 0.f};
    for (int kc = 0; kc < 512; kc += 32) {
#pragma unroll
        for (int i = 0; i < 32; ++i) {
            int lin = tid + i * 256;
            int e = lin >> 5, kk = lin & 31;
            h1s[e * 33 + kk] = half1[(size_t)(bb * TE + e) * 512 + kc + kk] * C2;
        }
        __syncthreads();
        const float* myh1 = h1s + tid * 33;
#pragma unroll 8
        for (int kk = 0; kk < 32; ++kk) {
            float u = myh1[kk];
            float w = W3[kc + kk];
#pragma unroll
            for (int r = 0; r < 4; ++r) {
                float t = 1.f - 2.f * __builtin_amdgcn_rcpf(__builtin_amdgcn_exp2f(u + h2s[r][kc + kk]) + 1.f);
                accs[r] += t * w;
            }
        }
        __syncthreads();
    }
    {
        const float b3v = b3[0];
#pragma unroll
        for (int r = 0; r < 4; ++r) sc[r][tid] = accs[r] + b3v;
    }
    __syncthreads();
    {
        const int r = tid >> 6, l = tid & 63;
        float4 v = *(const float4*)&sc[r][l * 4];
        float mx = fmaxf(fmaxf(v.x, v.y), fmaxf(v.z, v.w));
#pragma unroll
        for (int off = 32; off; off >>= 1) mx = fmaxf(mx, __shfl_xor(mx, off));
        const float L2E = 1.44269504089f;
        float e0 = __builtin_amdgcn_exp2f((v.x - mx) * L2E);
        float e1 = __builtin_amdgcn_exp2f((v.y - mx) * L2E);
        float e2 = __builtin_amdgcn_exp2f((v.z - mx) * L2E);
        float e3 = __builtin_amdgcn_exp2f((v.w - mx) * L2E);
        float s = e0 + e1 + e2 + e3;
#pragma unroll
        for (int off = 32; off; off >>= 1) s += __shfl_xor(s, off);
        float inv = 1.f / s;
        float4 p; p.x = e0 * inv; p.y = e1 * inv; p.z = e2 * inv; p.w = e3 * inv;
        *(float4*)&sc[r][l * 4] = p;
    }
    __syncthreads();   // h1s dead; av reuses @12288
    float acc[4][2] = {};
    for (int e0 = 0; e0 < TE; e0 += 8) {
#pragma unroll
        for (int i = 0; i < 16; ++i) {
            int lin = tid + i * 256;
            int e = lin >> 9, k = lin & 511;
            av[e][k] = att[(size_t)(bb * TE + e0 + e) * 512 + k];
        }
        __syncthreads();
#pragma unroll
        for (int ee = 0; ee < 8; ++ee) {
            float x0 = av[ee][tid], x1 = av[ee][tid + 256];
#pragma unroll
            for (int r = 0; r < 4; ++r) {
                float p = sc[r][e0 + ee];
                acc[r][0] += p * x0;
                acc[r][1] += p * x1;
            }
        }
        __syncthreads();
    }
#pragma unroll
    for (int r = 0; r < 4; ++r) {
        wgt[(size_t)(bb * TD + d0 + r) * 512 + tid] = acc[r][0];
        wgt[(size_t)(bb * TD + d0 + r) * 512 + tid + 256] = acc[r][1];
    }
}

// ---------------------------------------------------------------------------
// outgemm body (R10-identical). Pool 9472 B.
// ---------------------------------------------------------------------------
__device__ __forceinline__ void outgemm_body(const float* __restrict__ x,
    const float* __restrict__ wgt, const float* __restrict__ Wout,
    const float* __restrict__ bout, float* __restrict__ out, int m0, int ks,
    char* sm)
{
    float (*As2)[17] = (float(*)[17])sm;
    float (*Bs2)[80] = (float(*)[80])(sm + 4352);
    const int tid = threadIdx.x;
    const int tx = tid & 15, ty = tid >> 4;
    float acc[4][5] = {};
    for (int kt = 0; kt < 16; ++kt) {
        const int k0 = ks * 256 + kt * 16;
        const float* src = (k0 < 512) ? x : wgt;
        const int kk0 = (k0 < 512) ? k0 : (k0 - 512);
#pragma unroll
        for (int i = 0; i < 4; ++i) {
            int lin = tid + i * 256;
            int k = lin & 15, m = lin >> 4;
            As2[m][k] = src[(size_t)(m0 + m) * 512 + kk0 + k];
        }
#pragma unroll
        for (int i = 0; i < 5; ++i) {
            int lin = tid + i * 256;
            int n = lin % 80, k = lin / 80;
            Bs2[k][n] = Wout[(size_t)(k0 + k) * 80 + n];
        }
        __syncthreads();
#pragma unroll
        for (int kk = 0; kk < 16; ++kk) {
            float a[4], bv[5];
#pragma unroll
            for (int i = 0; i < 4; ++i) a[i] = As2[ty * 4 + i][kk];
#pragma unroll
            for (int j = 0; j < 5; ++j) bv[j] = Bs2[kk][tx * 5 + j];
#pragma unroll
            for (int i = 0; i < 4; ++i)
#pragma unroll
                for (int j = 0; j < 5; ++j) acc[i][j] += a[i] * bv[j];
        }
        __syncthreads();
    }
#pragma unroll
    for (int i = 0; i < 4; ++i) {
#pragma unroll
        for (int j = 0; j < 5; ++j) {
            float v = acc[i][j];
            if (ks == 0) v += bout[tx * 5 + j];
            atomicAdd(&out[(size_t)(m0 + ty * 4 + i) * 80 + tx * 5 + j], v);
        }
    }
}

// ---------------------------------------------------------------------------
// Combined kernel: LSTM (WGs 0-255) ∥ half1 GEMM (WGs 256-511).
// half1 is independent of the LSTM and hides under its spin-idle capacity.
// No grid sync inside — lstm WGs sync via hpub; gemm WGs exit when done.
// ---------------------------------------------------------------------------
__global__ __launch_bounds__(256, 1) void lstm_half1_k(
    const float* __restrict__ Zx, const float* __restrict__ Wr,
    float* __restrict__ hsx, u64* __restrict__ hpub,
    float* __restrict__ outh, float* __restrict__ outc,
    const float* __restrict__ att, const float* __restrict__ W1,
    const float* __restrict__ b1, float* __restrict__ half1)
{
    __shared__ __align__(16) char smem[8448];
    const int wg = blockIdx.x;
    if (wg < 256) {
        lstm_body(Zx, Wr, hsx, hpub, outh, outc, wg, smem);
    } else {
        int j = wg - 256;
        gemm_body(att, W1, b1, half1, 512, 512, (j >> 3) * 64, (j & 7) * 64, smem);
    }
}

// ---------------------------------------------------------------------------
// Standalone kernels (R10 chain + fallback path).
// ---------------------------------------------------------------------------
__global__ __launch_bounds__(256) void gemm_bias_k(const float* __restrict__ A,
    const float* __restrict__ B, const float* __restrict__ bias,
    float* __restrict__ C, int N, int K)
{
    __shared__ __align__(16) char pool[8448];
    gemm_body(A, B, bias, C, N, K, blockIdx.y * 64, blockIdx.x * 64, pool);
}

__global__ __launch_bounds__(256, 1) void lstm_k(const float* __restrict__ Zx,
    const float* __restrict__ Wr, float* __restrict__ hs,
    u64* __restrict__ hpub, float* __restrict__ outh, float* __restrict__ outc)
{
    __shared__ __align__(16) char pool[3072];
    lstm_body(Zx, Wr, hs, hpub, outh, outc, blockIdx.x, pool);
}

__global__ __launch_bounds__(256) void attn_k(const float* __restrict__ half1,
    const float* __restrict__ half2, const float* __restrict__ att,
    const float* __restrict__ W3, const float* __restrict__ b3,
    float* __restrict__ wgt)
{
    __shared__ __align__(16) char pool[46080];
    attn_body(half1, half2, att, W3, b3, wgt, blockIdx.x >> 6,
              (blockIdx.x & 63) * 4, pool);
}

__global__ __launch_bounds__(256) void outgemm_k(const float* __restrict__ x,
    const float* __restrict__ wgt, const float* __restrict__ Wout,
    const float* __restrict__ bout, float* __restrict__ out)
{
    __shared__ __align__(16) char pool[9472];
    outgemm_body(x, wgt, Wout, bout, out, blockIdx.x * 64, blockIdx.y, pool);
}

// ---------------------------------------------------------------------------
extern "C" void kernel_launch(void* const* d_in, const int* in_sizes, int n_in,
                              void* d_out, int out_size, void* d_ws, size_t ws_size,
                              hipStream_t stream)
{
    (void)in_sizes; (void)n_in; (void)out_size; (void)ws_size;
    const float* inputs = (const float*)d_in[0];   // [8,256,80]
    const float* att    = (const float*)d_in[1];   // [8,256,512]
    const float* Wk     = (const float*)d_in[2];   // [80,2048]
    const float* Wr     = (const float*)d_in[3];   // [512,2048]
    const float* lb     = (const float*)d_in[4];   // [2048]
    const float* W1     = (const float*)d_in[5];   // [512,512]
    const float* b1     = (const float*)d_in[6];   // [512]
    const float* W3     = (const float*)d_in[7];   // [512]
    const float* b3     = (const float*)d_in[8];   // [1]
    const float* Wout   = (const float*)d_in[9];   // [1024,80]
    const float* bout   = (const float*)d_in[10];  // [80]

    float* out  = (float*)d_out;          // [2048,80]
    float* outh = out + 2048 * 80;        // [8,512]
    float* outc = outh + 8 * 512;         // [8,512]

    char* ws = (char*)d_ws;
    float* Zx    = (float*)(ws);                      // 16 MB  [2048,2048]
    float* half1 = (float*)(ws + (16u << 20));        // 4 MB   [2048,512]
    float* half2 = (float*)(ws + (20u << 20));        // 4 MB   [2048,512]
    float* hsx   = (float*)(ws + (24u << 20));        // 4 MB   [2048,512]
    float* wgt   = (float*)(ws + (28u << 20));        // 4 MB   [2048,512]
    u64*   hpub  = (u64*)(ws + (32u << 20));          // 64 KB  hpub[2][8][512]

    // zero hpub tags; zero out (atomicAdd target)
    (void)hipMemsetAsync(ws + (32u << 20), 0, 65536, stream);
    (void)hipMemsetAsync(d_out, 0, (size_t)2048 * 80 * 4, stream);

    // Zx = inputs @ Wk + lstm_b   [2048,80]x[80,2048]
    gemm_bias_k<<<dim3(32, 32), 256, 0, stream>>>(inputs, Wk, lb, Zx, 2048, 80);

    // LSTM ∥ half1 (one cooperative launch, 512 WGs)
    void* cargs[] = { (void*)&Zx, (void*)&Wr, (void*)&hsx, (void*)&hpub,
                      (void*)&outh, (void*)&outc, (void*)&att, (void*)&W1,
                      (void*)&b1, (void*)&half1 };
    hipError_t cerr = hipLaunchCooperativeKernel((void*)lstm_half1_k, dim3(512),
                                                 dim3(256), cargs, 0, stream);
    if (cerr != hipSuccess) {
        // Fallback: serial half1 + cooperative lstm (R10 chain).
        gemm_bias_k<<<dim3(8, 32), 256, 0, stream>>>(att, W1, b1, half1, 512, 512);
        void* largs[] = { (void*)&Zx, (void*)&Wr, (void*)&hsx, (void*)&hpub,
                          (void*)&outh, (void*)&outc };
        (void)hipLaunchCooperativeKernel((void*)lstm_k, dim3(256), dim3(256), largs, 0, stream);
    }

    // half2 = x @ W1 + b1
    gemm_bias_k<<<dim3(8, 32), 256, 0, stream>>>(hsx, W1, b1, half2, 512, 512);
    // fused scores/softmax/weighted
    attn_k<<<dim3(512), 256, 0, stream>>>(half1, half2, att, W3, b3, wgt);
    // out = [x | weighted] @ Wout + bout
    outgemm_k<<<dim3(32, 4), 256, 0, stream>>>(hsx, wgt, Wout, bout, out);
}